// Round 9
// baseline (888.469 us; speedup 1.0000x reference)
//
#include <hip/hip_runtime.h>
#include <hip/hip_bf16.h>

// Problem: N=4,C=64,F=100,T=200,H=16 ; B=N*F=400, BT=80000
// Pipeline per b-chunk (NB rows): ln1 (fp32->bf16 x) -> xg GEMM (MFMA bf16,
//   bf16 out, gate-group-major layout) -> LSTM recurrence (MFMA: 16 chains/
//   wave, Whh as 4 A-fragments = 16 VGPRs, h->B via 4 packed shfls, xg as C)
//   -> attention (multiplicative causal mask BEFORE softmax, suffix-V trick)
//   -> combine+LN2+complex linear+LN3+PReLU+residual.
// ws: header 262144 B (bihh @0, Wih-bf16 @8192, Whh-bf16 @204800), per chunk:
//   xr bf16 [NB][200][64], xi same, xg bf16 [24][200][NB][64] (j=g*16+k),
//   h f32 [24][NB][200][16], att f32 [8][NB][200][16].
// Total = 262144 + NB*1,075,200.

typedef __attribute__((ext_vector_type(8))) short bf16x8;
typedef __attribute__((ext_vector_type(4))) float f32x4;

static __device__ __forceinline__ float bf2f(unsigned short u) {
  return __uint_as_float(((unsigned)u) << 16);
}
static __device__ __forceinline__ unsigned short f2bfu(float x) {
  __hip_bfloat16 h = __float2bfloat16(x);
  return *(unsigned short*)&h;
}
static __device__ __forceinline__ unsigned packbf(float lo, float hi) {
  return ((unsigned)f2bfu(hi) << 16) | (unsigned)f2bfu(lo);
}
static __device__ __forceinline__ float sigf(float x) {
  return __fdividef(1.f, 1.f + __expf(-x));
}
static __device__ __forceinline__ float tanh_(float x) {
  return 1.f - __fdividef(2.f, __expf(2.f * x) + 1.f);  // safe at +-inf
}

// ---------------- kernel A: LN1 over C -> xr/xi bf16 [bl][t][c]
__global__ __launch_bounds__(256) void k_ln1(const float* __restrict__ in,
    const float* __restrict__ w, const float* __restrict__ bsh,
    unsigned short* __restrict__ xr, unsigned short* __restrict__ xi, int b0) {
  __shared__ float is[64][101];   // [c][(tloc,ri)]
  __shared__ float os[100][65];   // [(tloc,ri)][c]
  int bid = blockIdx.x;
  int nfl = bid >> 2, tile = bid & 3;         // NB nf-local x 4 tiles of 50 t
  int nf = b0 + nfl;
  int t0 = tile * 50;
  int n = nf / 100, f = nf - n * 100;
  int tid = threadIdx.x;
  for (int i = 0; i < 7; ++i) {               // 64 rows x 25 float4
    int idx = tid + i * 256;
    if (idx < 1600) {
      int c = idx / 25, q = idx - c * 25;
      float4 v = *(const float4*)(in + (size_t)((n * 64 + c) * 100 + f) * 400
                                  + t0 * 2 + q * 4);
      is[c][q*4+0] = v.x; is[c][q*4+1] = v.y; is[c][q*4+2] = v.z; is[c][q*4+3] = v.w;
    }
  }
  __syncthreads();
  if (tid < 100) {
    float s = 0.f, ss = 0.f;
    #pragma unroll
    for (int c = 0; c < 64; ++c) { float v = is[c][tid]; s += v; ss += v * v; }
    float mean = s * 0.015625f;
    float var  = ss * 0.015625f - mean * mean;
    float rstd = rsqrtf(var + 1e-5f);
    #pragma unroll
    for (int c = 0; c < 64; ++c)
      os[tid][c] = (is[c][tid] - mean) * rstd * w[c] + bsh[c];
  }
  __syncthreads();
  for (int ri = 0; ri < 2; ++ri) {
    unsigned short* dst = ri ? xi : xr;
    for (int i = 0; i < 4; ++i) {             // 50 rows x 16 ushort4 per ri
      int idx = tid + i * 256;
      if (idx < 800) {
        int t = idx >> 4, q = idx & 15;
        ushort4 v;
        v.x = f2bfu(os[t*2+ri][q*4+0]); v.y = f2bfu(os[t*2+ri][q*4+1]);
        v.z = f2bfu(os[t*2+ri][q*4+2]); v.w = f2bfu(os[t*2+ri][q*4+3]);
        *(ushort4*)(dst + ((size_t)nfl * 200 + t0 + t) * 64 + q * 4) = v;
      }
    }
  }
}

// ---------------- prep: bihh = bih + bhh ; wbf = bf16(Wih) ; whb = bf16(Whh)
__global__ void k_prep(const float* __restrict__ bih, const float* __restrict__ bhh,
                       const float* __restrict__ Wih, const float* __restrict__ Whh,
                       float* __restrict__ bihh, unsigned short* __restrict__ wbf,
                       unsigned short* __restrict__ whb) {
  int i = blockIdx.x * 256 + threadIdx.x;
  if (i < 1536) bihh[i] = bih[i] + bhh[i];
  if (i < 98304) wbf[i] = f2bfu(Wih[i]);
  if (i < 24576) whb[i] = f2bfu(Whh[i]);
}

// ---------------- kernel B: xg = x_sel @ Wih[l]^T + bihh[l] via MFMA bf16.
// Output layout per (l,t,b): 64 bf16, j = g*16 + k (gate-group-major).
__global__ __launch_bounds__(256) void k_xg(const unsigned short* __restrict__ xr,
    const unsigned short* __restrict__ xi, const unsigned short* __restrict__ wbf,
    const float* __restrict__ bihh, unsigned short* __restrict__ xg,
    int M, int NB, int nsb) {
  int tid = threadIdx.x;
  int wave = tid >> 6, lane = tid & 63;
  int bid = blockIdx.x;
  int l = bid / nsb, sb = bid - l * nsb;
  int sub = sb * 4 + wave;
  int m0 = sub * 16;
  if (m0 >= M) return;
  int sel = (0xE54770 >> l) & 1;                 // per-lstm real/imag selection
  const unsigned short* xs = sel ? xi : xr;
  int n = lane & 15, q = lane >> 4;
  int mr = m0 + n; if (mr >= M) mr = M - 1;      // clamp A rows (stores guarded)
  const unsigned short* xrow = xs + (size_t)mr * 64;
  bf16x8 a0 = *(const bf16x8*)(xrow + q * 8);        // c = q*8+e
  bf16x8 a1 = *(const bf16x8*)(xrow + 32 + q * 8);   // c = 32+q*8+e
  int mq = m0 + q * 4;
  int bl = mq / 200, tt = mq - bl * 200;
  size_t ob[4]; bool okm[4];
  #pragma unroll
  for (int r = 0; r < 4; ++r) {
    okm[r] = (mq + r) < M;
    ob[r] = ((size_t)(l * 200 + tt) * NB + bl) * 64;
    ++tt; if (tt == 200) { tt = 0; ++bl; }
  }
  const unsigned short* wbase = wbf + l * 4096;
  f32x4 acc[4];
  float bi[4];
  #pragma unroll
  for (int jt = 0; jt < 4; ++jt) {               // j = jt*16 + n ; k=n, g=jt
    const unsigned short* wrow = wbase + (jt * 16 + n) * 64;
    bf16x8 b0 = *(const bf16x8*)(wrow + q * 8);
    bf16x8 b1 = *(const bf16x8*)(wrow + 32 + q * 8);
    f32x4 a = {0.f, 0.f, 0.f, 0.f};
    a = __builtin_amdgcn_mfma_f32_16x16x32_bf16(a0, b0, a, 0, 0, 0);
    acc[jt] = __builtin_amdgcn_mfma_f32_16x16x32_bf16(a1, b1, a, 0, 0, 0);
    bi[jt] = bihh[l * 64 + jt * 16 + n];
  }
  #pragma unroll
  for (int r = 0; r < 4; ++r) {
    if (!okm[r]) continue;
    #pragma unroll
    for (int jt = 0; jt < 4; ++jt)               // [b][jt*16+n], 16-lane rows
      xg[ob[r] + jt * 16 + n] = f2bfu(acc[jt][r] + bi[jt]);
  }
}

// ---------------- kernel R: LSTM recurrence via MFMA. One wave = 16 chains
// of one l. A-frag (loop-invariant, 16 VGPRs total) = Whh gate-group g:
// A[m=gate-idx][k], q>=2 zero (K=32 pad). B (per step) = h[k][chain n], built
// from D-layout state with 4 packed-bf16 shfls. C = xg_t (bias pre-added).
// D: lane (q,n) holds gates 4q+r of chain n for all 4 groups -> i,f,g,o of
// each (chain,k) in the SAME lane/reg: cell update is per-lane VALU only.
__global__ __launch_bounds__(64) void k_lstm(const unsigned short* __restrict__ xg,
    const unsigned short* __restrict__ whb, float* __restrict__ hbuf,
    int NB, int wpl) {
  int lane = threadIdx.x;
  int n = lane & 15, q = lane >> 4;
  int wid = blockIdx.x;                   // 24 * wpl blocks (1 wave each)
  int l = wid / wpl, wg = wid - l * wpl;
  int b = wg * 16 + n;
  bool live = b < NB;
  int bc = live ? b : NB - 1;
  bf16x8 Z = {0, 0, 0, 0, 0, 0, 0, 0};
  const unsigned short* wb = whb + (size_t)l * 1024;   // [j=g*16+gi][k]
  bf16x8 A0 = (q < 2) ? *(const bf16x8*)(wb + (0 * 16 + n) * 16 + q * 8) : Z;
  bf16x8 A1 = (q < 2) ? *(const bf16x8*)(wb + (1 * 16 + n) * 16 + q * 8) : Z;
  bf16x8 A2 = (q < 2) ? *(const bf16x8*)(wb + (2 * 16 + n) * 16 + q * 8) : Z;
  bf16x8 A3 = (q < 2) ? *(const bf16x8*)(wb + (3 * 16 + n) * 16 + q * 8) : Z;
  asm volatile("" : "+v"(A0), "+v"(A1), "+v"(A2), "+v"(A3));  // keep resident
  const unsigned short* xb = xg + ((size_t)l * 200 * NB + bc) * 64 + q * 4;
  size_t tstr = (size_t)NB * 64;
  float* hp = hbuf + ((size_t)l * NB + bc) * 3200 + q * 4;
  int srcA = ((q & 1) ? 32 : 0) + n;      // h-owner lanes for this q's k-range
  int srcB = srcA + 16;
  f32x4 h = {0.f, 0.f, 0.f, 0.f}, c = {0.f, 0.f, 0.f, 0.f};
  // depth-2 prefetch of xg (C operand), 4 gate groups
  ushort4 c0 = *(const ushort4*)(xb +  0), c1 = *(const ushort4*)(xb + 16);
  ushort4 c2 = *(const ushort4*)(xb + 32), c3 = *(const ushort4*)(xb + 48);
  ushort4 n0 = *(const ushort4*)(xb + tstr +  0), n1 = *(const ushort4*)(xb + tstr + 16);
  ushort4 n2 = *(const ushort4*)(xb + tstr + 32), n3 = *(const ushort4*)(xb + tstr + 48);
  for (int t = 0; t < 200; ++t) {
    // B-frag: lane (q,n) needs h[chain n][k=q*8+e] -> packed pairs from
    // owner lanes (2q,n) and (2q+1,n) (q>=2 garbage, A zero there)
    unsigned ph0 = packbf(h[0], h[1]);    // k = 4q'+0, 4q'+1 of owner q'
    unsigned ph1 = packbf(h[2], h[3]);    // k = 4q'+2, 4q'+3
    unsigned dw0 = (unsigned)__shfl((int)ph0, srcA, 64);
    unsigned dw1 = (unsigned)__shfl((int)ph1, srcA, 64);
    unsigned dw2 = (unsigned)__shfl((int)ph0, srcB, 64);
    unsigned dw3 = (unsigned)__shfl((int)ph1, srcB, 64);
    uint4 bu = {dw0, dw1, dw2, dw3};
    bf16x8 B = *(bf16x8*)&bu;
    f32x4 C0 = {bf2f(c0.x), bf2f(c0.y), bf2f(c0.z), bf2f(c0.w)};
    f32x4 C1 = {bf2f(c1.x), bf2f(c1.y), bf2f(c1.z), bf2f(c1.w)};
    f32x4 C2 = {bf2f(c2.x), bf2f(c2.y), bf2f(c2.z), bf2f(c2.w)};
    f32x4 C3 = {bf2f(c3.x), bf2f(c3.y), bf2f(c3.z), bf2f(c3.w)};
    f32x4 D0 = __builtin_amdgcn_mfma_f32_16x16x32_bf16(A0, B, C0, 0, 0, 0);
    f32x4 D1 = __builtin_amdgcn_mfma_f32_16x16x32_bf16(A1, B, C1, 0, 0, 0);
    f32x4 D2 = __builtin_amdgcn_mfma_f32_16x16x32_bf16(A2, B, C2, 0, 0, 0);
    f32x4 D3 = __builtin_amdgcn_mfma_f32_16x16x32_bf16(A3, B, C3, 0, 0, 0);
    #pragma unroll
    for (int r = 0; r < 4; ++r) {
      float ig = sigf(D0[r]);
      float fg = sigf(D1[r]);
      float gg = tanh_(D2[r]);
      float og = sigf(D3[r]);
      float cc = fg * c[r] + ig * gg;
      c[r] = cc;
      h[r] = og * tanh_(cc);
    }
    if (live) *(f32x4*)(hp + (size_t)t * 16) = h;   // h[b][t][4q..4q+3]
    // rotate prefetch
    c0 = n0; c1 = n1; c2 = n2; c3 = n3;
    int tn = t + 2; if (tn > 199) tn = 199;
    const unsigned short* np = xb + (size_t)tn * tstr;
    n0 = *(const ushort4*)(np +  0); n1 = *(const ushort4*)(np + 16);
    n2 = *(const ushort4*)(np + 32); n3 = *(const ushort4*)(np + 48);
  }
}

// ---------------- kernel C: attention per (branch, bl). Multiplicative causal
// mask before softmax: masked s get weight exp(0); handled via suffix-V init.
__global__ __launch_bounds__(256) void k_attn(const float* __restrict__ hbuf,
                                              float* __restrict__ att, int NB) {
  __shared__ float Q[200][17];
  __shared__ float K[200][16];
  __shared__ float V[200][16];
  __shared__ float Vs[200][17];
  int bid = blockIdx.x;                 // 8 br x NB
  int br = bid / NB, b = bid - br * NB;
  int tid = threadIdx.x;
  const float* qg = hbuf + ((size_t)(br * 3 + 0) * NB + b) * 3200;
  const float* kg = hbuf + ((size_t)(br * 3 + 1) * NB + b) * 3200;
  const float* vg = hbuf + ((size_t)(br * 3 + 2) * NB + b) * 3200;
  for (int i = 0; i < 4; ++i) {         // 200 rows x 4 f4 each of Q,K,V
    int idx = tid + i * 256;
    if (idx < 800) {
      int t = idx >> 2, q = idx & 3;
      float4 a = *(const float4*)(qg + t * 16 + q * 4);
      Q[t][q*4+0] = a.x; Q[t][q*4+1] = a.y; Q[t][q*4+2] = a.z; Q[t][q*4+3] = a.w;
      *(float4*)&K[t][q * 4] = *(const float4*)(kg + t * 16 + q * 4);
      *(float4*)&V[t][q * 4] = *(const float4*)(vg + t * 16 + q * 4);
    }
  }
  __syncthreads();
  if (tid < 16) {                       // suffix sums of V
    float acc = 0.f;
    Vs[199][tid] = 0.f;
    for (int t = 198; t >= 0; --t) { acc += V[t + 1][tid]; Vs[t][tid] = acc; }
  }
  __syncthreads();
  if (tid < 200) {
    int t = tid;
    float q0[16], va[16];
    #pragma unroll
    for (int k = 0; k < 16; ++k) q0[k] = Q[t][k] * 0.25f;   // fold /sqrt(16)
    #pragma unroll
    for (int k = 0; k < 16; ++k) va[k] = Vs[t][k];          // masked: weight exp(0)=1
    float S = (float)(199 - t);
    for (int s = 0; s <= t; ++s) {
      float e = 0.f;
      #pragma unroll
      for (int k = 0; k < 16; ++k) e += q0[k] * K[s][k];
      float wgt = __expf(e);
      S += wgt;
      #pragma unroll
      for (int k = 0; k < 16; ++k) va[k] += wgt * V[s][k];
    }
    float inv = __fdividef(1.f, S);
    float* dst = att + (((size_t)br * NB + b) * 200 + t) * 16;
    #pragma unroll
    for (int q = 0; q < 4; ++q) {
      float4 v; v.x = va[q*4+0]*inv; v.y = va[q*4+1]*inv;
      v.z = va[q*4+2]*inv; v.w = va[q*4+3]*inv;
      *(float4*)(dst + q * 4) = v;
    }
  }
}

// ---------------- kernel D: combine branches + LN2 + complex linear + LN3 +
// PReLU + residual, with LDS transpose for coalesced [N,C,F,T,2] IO.
__global__ __launch_bounds__(256) void k_out(const float* __restrict__ att,
    const float* __restrict__ in,
    const float* __restrict__ ln2w, const float* __restrict__ ln2b,
    const float* __restrict__ lrw, const float* __restrict__ lrb,
    const float* __restrict__ liw, const float* __restrict__ lib,
    const float* __restrict__ ln3w, const float* __restrict__ ln3b,
    const float* __restrict__ pa, float* __restrict__ out, int b0, int NB) {
  __shared__ float as_[8][40][17];
  __shared__ float ys[40][2][17];
  __shared__ float zs[64][81];
  int bid = blockIdx.x;                 // NB nf-local x 5 tiles of 40 t
  int nfl = bid / 5, tile = bid - nfl * 5;
  int nf = b0 + nfl;
  int t0 = tile * 40;
  int n = nf / 100, f = nf - n * 100;
  int tid = threadIdx.x;
  for (int i = 0; i < 5; ++i) {         // att: 8 br x 40 t x 4 f4
    int idx = tid + i * 256;
    int br = idx / 160, r = idx - br * 160;
    int t = r >> 2, q = r & 3;
    float4 v = *(const float4*)(att + (((size_t)br * NB + nfl) * 200 + t0 + t) * 16 + q * 4);
    as_[br][t][q*4+0] = v.x; as_[br][t][q*4+1] = v.y;
    as_[br][t][q*4+2] = v.z; as_[br][t][q*4+3] = v.w;
  }
  __syncthreads();
  if (tid < 80) {                       // combine + LN2 per (t,ri)
    int t = tid >> 1, ri = tid & 1;
    float vv[16]; float s = 0.f, ss = 0.f;
    #pragma unroll
    for (int k = 0; k < 16; ++k) {
      float v;
      if (ri == 0) v = as_[0][t][k] - as_[1][t][k] - as_[2][t][k] - as_[3][t][k];
      else         v = as_[4][t][k] + as_[5][t][k] + as_[6][t][k] - as_[7][t][k];
      vv[k] = v; s += v; ss += v * v;
    }
    float mean = s * 0.0625f;
    float var  = ss * 0.0625f - mean * mean;
    float rstd = rsqrtf(var + 1e-5f);
    #pragma unroll
    for (int k = 0; k < 16; ++k)
      ys[t][ri][k] = (vv[k] - mean) * rstd * ln2w[k] + ln2b[k];
  }
  __syncthreads();
  // complex linear 16->64 + LN3 over c (wave = 64 lanes = c) + PReLU
  int wv = tid >> 6, cc = tid & 63;
  float lr[16], li[16];
  #pragma unroll
  for (int q = 0; q < 4; ++q) {
    float4 v = *(const float4*)(lrw + cc * 16 + q * 4);
    lr[q*4+0] = v.x; lr[q*4+1] = v.y; lr[q*4+2] = v.z; lr[q*4+3] = v.w;
    float4 u = *(const float4*)(liw + cc * 16 + q * 4);
    li[q*4+0] = u.x; li[q*4+1] = u.y; li[q*4+2] = u.z; li[q*4+3] = u.w;
  }
  float brc = lrb[cc], bic = lib[cc];
  float w3 = ln3w[cc], b3 = ln3b[cc];
  float aP = pa[0];
  for (int tt = wv; tt < 40; tt += 4) {
    float zr = brc - bic, zi = brc + bic;
    #pragma unroll
    for (int k = 0; k < 16; ++k) {
      float yr = ys[tt][0][k], yi = ys[tt][1][k];
      zr += yr * lr[k] - yi * li[k];
      zi += yi * lr[k] + yr * li[k];
    }
    float s1 = zr, s2 = zr * zr, s3 = zi, s4 = zi * zi;
    #pragma unroll
    for (int m = 1; m < 64; m <<= 1) {
      s1 += __shfl_xor(s1, m, 64);
      s2 += __shfl_xor(s2, m, 64);
      s3 += __shfl_xor(s3, m, 64);
      s4 += __shfl_xor(s4, m, 64);
    }
    float mr = s1 * 0.015625f, vr = s2 * 0.015625f - mr * mr;
    float mi = s3 * 0.015625f, vi = s4 * 0.015625f - mi * mi;
    float r1 = (zr - mr) * rsqrtf(vr + 1e-5f) * w3 + b3;
    float r2 = (zi - mi) * rsqrtf(vi + 1e-5f) * w3 + b3;
    r1 = r1 >= 0.f ? r1 : aP * r1;
    r2 = r2 >= 0.f ? r2 : aP * r2;
    zs[cc][tt * 2 + 0] = r1;
    zs[cc][tt * 2 + 1] = r2;
  }
  __syncthreads();
  for (int i = 0; i < 5; ++i) {         // residual + coalesced write
    int idx = tid + i * 256;            // 64 c x 20 f4
    int c = idx / 20, q = idx - c * 20;
    size_t gaddr = (size_t)((n * 64 + c) * 100 + f) * 400 + t0 * 2 + q * 4;
    float4 v = *(const float4*)(in + gaddr);
    float4 z;
    z.x = zs[c][q*4+0] + v.x; z.y = zs[c][q*4+1] + v.y;
    z.z = zs[c][q*4+2] + v.z; z.w = zs[c][q*4+3] + v.w;
    *(float4*)(out + gaddr) = z;
  }
}

extern "C" void kernel_launch(void* const* d_in, const int* in_sizes, int n_in,
                              void* d_out, int out_size, void* d_ws, size_t ws_size,
                              hipStream_t stream) {
  (void)in_sizes; (void)n_in; (void)out_size;
  const float* inputs = (const float*)d_in[0];
  const float* Wih  = (const float*)d_in[1];
  const float* Whh  = (const float*)d_in[2];
  const float* bih  = (const float*)d_in[3];
  const float* bhh  = (const float*)d_in[4];
  const float* ln1w = (const float*)d_in[5];
  const float* ln1b = (const float*)d_in[6];
  const float* ln2w = (const float*)d_in[7];
  const float* ln2b = (const float*)d_in[8];
  const float* lrw  = (const float*)d_in[9];
  const float* lrb  = (const float*)d_in[10];
  const float* liw  = (const float*)d_in[11];
  const float* lib  = (const float*)d_in[12];
  const float* ln3w = (const float*)d_in[13];
  const float* ln3b = (const float*)d_in[14];
  const float* pa   = (const float*)d_in[15];
  float* out = (float*)d_out;
  char* ws = (char*)d_ws;

  // pick largest chunk NB (400,200,100,50,25) whose buffers fit ws_size
  int NB = 400;
  while (NB > 25 && 262144ull + (size_t)NB * 1075200ull > ws_size) NB /= 2;
  int nch = 400 / NB;

  float* bihh = (float*)(ws + 0);                        // 6 KB
  unsigned short* wbf = (unsigned short*)(ws + 8192);    // 192 KB bf16 Wih
  unsigned short* whb = (unsigned short*)(ws + 204800);  // 48 KB bf16 Whh
  size_t o_xr = 262144;
  size_t o_xi = o_xr + (size_t)NB * 25600;
  size_t o_xg = o_xi + (size_t)NB * 25600;
  size_t o_h  = o_xg + (size_t)NB * 614400;
  size_t o_at = o_h  + (size_t)NB * 307200;
  unsigned short* xr = (unsigned short*)(ws + o_xr);
  unsigned short* xi = (unsigned short*)(ws + o_xi);
  unsigned short* xg = (unsigned short*)(ws + o_xg);
  float* hbuf = (float*)(ws + o_h);
  float* att  = (float*)(ws + o_at);

  k_prep<<<384, 256, 0, stream>>>(bih, bhh, Wih, Whh, bihh, wbf, whb);
  int M = NB * 200;
  int nsb = (M + 63) >> 6;              // 64 m-rows per block (4 waves x 16)
  int wpl = (NB + 15) >> 4;             // 16-chain waves per l
  for (int ch = 0; ch < nch; ++ch) {
    int b0 = ch * NB;
    k_ln1 <<<NB * 4,    256, 0, stream>>>(inputs, ln1w, ln1b, xr, xi, b0);
    k_xg  <<<24 * nsb,  256, 0, stream>>>(xr, xi, wbf, bihh, xg, M, NB, nsb);
    k_lstm<<<24 * wpl,   64, 0, stream>>>(xg, whb, hbuf, NB, wpl);
    k_attn<<<8 * NB,    256, 0, stream>>>(hbuf, att, NB);
    k_out <<<NB * 5,    256, 0, stream>>>(att, inputs, ln2w, ln2b, lrw, lrb,
                                          liw, lib, ln3w, ln3b, pa, out, b0, NB);
  }
}